// Round 9
// baseline (158.613 us; speedup 1.0000x reference)
//
#include <hip/hip_runtime.h>

#define NTOK 8192
#define DDIM 1024
#define NEXP 16
#define NPAIR 136   // E*(E+1)/2 pairs with e<=f
#define XROW 1032   // LDS x-tile row stride (pad 8 floats)
#define NBLK 1024   // fused blocks (8 tokens each)

typedef float vfloat4 __attribute__((ext_vector_type(4)));

// ws layout (floats):
//   gwT4  [4096 float4] = 16384 f   (transposed gate)
//   s_glob[1024]                    (final x^2 column sums)
//   G_part[16*136]
//   sred  [NBLK*1024]               (per-block x^2 partials, plain stores)
#define WS_GWT 0
#define WS_SG  16384
#define WS_GP  (16384 + DDIM)
#define WS_SRED (16384 + DDIM + 16 * NPAIR)
#define WS_NEED_F (WS_SRED + NBLK * DDIM)

// ---------------------------------------------------------------------------
// Prep: transpose gate_w [16][1024] -> gwT4[d4][e]; zero s_glob.
// ---------------------------------------------------------------------------
__global__ __launch_bounds__(256) void moe_prep(
    const float* __restrict__ gate_w,
    float* __restrict__ ws)
{
    const int gid = blockIdx.x * 256 + threadIdx.x;   // 0..4095
    const int e = gid & 15;
    const int d4 = gid >> 4;
    const float4* gw4 = (const float4*)gate_w;
    ((float4*)(ws + WS_GWT))[d4 * 16 + e] = gw4[e * 256 + d4];
    if (gid < DDIM) (ws + WS_SG)[gid] = 0.f;
}

// ---------------------------------------------------------------------------
// Fused: 1024 blocks x 256 thr, 8 tokens/block, 2 tokens/wave.
// A: x-tile -> LDS once (coalesced); thread t owns d-cols 4t..4t+3 -> x^2
//    partials stored as ONE plain float4 per thread (no atomics) when ws
//    allows; else direct atomics (fallback).
// B: routing: lane=(g tok, h half, e expert); 512-d half-dot; x from LDS
//    broadcast, gate streamed from global in transposed-coalesced layout
//    (4x256B segments per wave-instr). Single barrier, no chunk barriers;
//    launch_bounds(256,2) gives the allocator room to pipeline ~16 loads.
// C: stable top2 + sigmoid weights (softmax denom cancels).
// D: combine from LDS x, nontemporal out stores.
// ---------------------------------------------------------------------------
template<bool SRED>
__global__ __launch_bounds__(256, 2) void moe_fused(
    const float* __restrict__ x,
    const float* __restrict__ gate_b,
    const float* __restrict__ sh,
    const float* __restrict__ re,
    float* __restrict__ out,
    float* __restrict__ ws)
{
    __shared__ float xt[8][XROW];

    const int t = threadIdx.x;
    const int b = blockIdx.x;
    const float4* gwT4 = (const float4*)(ws + WS_GWT);

    // ---- A: stage 8 token rows + x^2 partials for owned columns ----
    float4 ss = make_float4(0.f, 0.f, 0.f, 0.f);
    {
        const float4* x4 = (const float4*)x + (size_t)b * 2048;
        #pragma unroll
        for (int i = 0; i < 8; ++i) {
            float4 v = x4[i * 256 + t];
            *(float4*)&xt[i][4 * t] = v;
            ss.x = fmaf(v.x, v.x, ss.x);
            ss.y = fmaf(v.y, v.y, ss.y);
            ss.z = fmaf(v.z, v.z, ss.z);
            ss.w = fmaf(v.w, v.w, ss.w);
        }
    }
    if (SRED) {
        ((float4*)(ws + WS_SRED + (size_t)b * DDIM))[t] = ss;  // plain store
    } else {
        float* sg = ws + WS_SG;
        atomicAdd(&sg[4 * t + 0], ss.x);
        atomicAdd(&sg[4 * t + 1], ss.y);
        atomicAdd(&sg[4 * t + 2], ss.z);
        atomicAdd(&sg[4 * t + 3], ss.w);
    }
    __syncthreads();

    const int lane = t & 63;
    const int wave = t >> 6;
    const int e = lane & 15;
    const int h = (lane >> 4) & 1;
    const int g = lane >> 5;
    const int tokL = wave * 2 + g;

    // ---- B: routing half-dot, dual accumulators for ILP ----
    const float* xrow = &xt[tokL][h * 512];
    const float4* gt = gwT4 + h * 128 * 16 + e;
    float4 acc0 = make_float4(0.f, 0.f, 0.f, 0.f);
    float4 acc1 = make_float4(0.f, 0.f, 0.f, 0.f);
    #pragma unroll 8
    for (int i = 0; i < 128; i += 2) {
        float4 xv0 = *(const float4*)(xrow + 4 * i);
        float4 gv0 = gt[i * 16];
        float4 xv1 = *(const float4*)(xrow + 4 * i + 4);
        float4 gv1 = gt[i * 16 + 16];
        acc0.x = fmaf(xv0.x, gv0.x, acc0.x);
        acc0.y = fmaf(xv0.y, gv0.y, acc0.y);
        acc0.z = fmaf(xv0.z, gv0.z, acc0.z);
        acc0.w = fmaf(xv0.w, gv0.w, acc0.w);
        acc1.x = fmaf(xv1.x, gv1.x, acc1.x);
        acc1.y = fmaf(xv1.y, gv1.y, acc1.y);
        acc1.z = fmaf(xv1.z, gv1.z, acc1.z);
        acc1.w = fmaf(xv1.w, gv1.w, acc1.w);
    }
    float s = ((acc0.x + acc0.y) + (acc0.z + acc0.w))
            + ((acc1.x + acc1.y) + (acc1.z + acc1.w));
    s += __shfl_xor(s, 16, 64);       // merge d-halves
    s += gate_b[e];

    // ---- C: stable top2 over this token's 16 expert lanes ----
    float v0 = -3.0e38f, v1 = -3.0e38f;
    int i0 = 0, i1 = 0;
    const int base = lane & 32;
    #pragma unroll
    for (int j = 0; j < NEXP; ++j) {
        float lv = __shfl(s, base + j, 64);
        if (lv > v0)      { v1 = v0; i1 = i0; v0 = lv; i0 = j; }
        else if (lv > v1) { v1 = lv; i1 = j; }
    }
    float ex = __expf(v1 - v0);       // softmax denom cancels in renorm
    float w0 = 1.f / (1.f + ex);
    float w1 = ex * w0;

    // ---- D: combine this wave's 2 tokens ----
    const float4* s0 = (const float4*)sh;
    const float4* s1 = (const float4*)(sh + DDIM);
    #pragma unroll
    for (int tk = 0; tk < 2; ++tk) {
        const int src = tk << 5;
        float a0 = __shfl(w0, src, 64);
        float a1 = __shfl(w1, src, 64);
        int   e0 = __shfl(i0, src, 64);
        int   e1 = __shfl(i1, src, 64);
        const int tokC = wave * 2 + tk;
        const float4* xr = (const float4*)&xt[tokC][0];
        const float4* r0 = (const float4*)(re + (size_t)e0 * DDIM);
        const float4* r1 = (const float4*)(re + (size_t)e1 * DDIM);
        vfloat4* o = (vfloat4*)(out + ((size_t)b * 8 + tokC) * DDIM);
        #pragma unroll
        for (int j = 0; j < 4; ++j) {
            const int idx = lane + 64 * j;
            float4 xv = xr[idx];
            float4 p  = s0[idx];
            float4 q  = s1[idx];
            float4 b0 = r0[idx];
            float4 b1 = r1[idx];
            vfloat4 r;
            r.x = xv.x * ((p.x + q.x) + a0 * b0.x + a1 * b1.x);
            r.y = xv.y * ((p.y + q.y) + a0 * b0.y + a1 * b1.y);
            r.z = xv.z * ((p.z + q.z) + a0 * b0.z + a1 * b1.z);
            r.w = xv.w * ((p.w + q.w) + a0 * b0.w + a1 * b1.w);
            __builtin_nontemporal_store(r, &o[idx]);
        }
    }
}

// ---------------------------------------------------------------------------
// Reduce sred[NBLK][1024] -> s_glob[1024]. 32 blocks x 256 thr, no atomics:
// block owns d-cols [32b, 32b+32); thread (rg=t>>5, c=t&31) strides rows.
// ---------------------------------------------------------------------------
__global__ __launch_bounds__(256) void moe_sreduce(
    float* __restrict__ ws)
{
    __shared__ float part[8][33];
    const int t = threadIdx.x;
    const int d0 = blockIdx.x * 32;
    const int c = t & 31;
    const int rg = t >> 5;
    const float* sred = ws + WS_SRED;
    float a = 0.f;
    for (int r = rg; r < NBLK; r += 8)
        a += sred[(size_t)r * DDIM + d0 + c];
    part[rg][c] = a;
    __syncthreads();
    if (t < 32) {
        float v = ((part[0][t] + part[1][t]) + (part[2][t] + part[3][t]))
                + ((part[4][t] + part[5][t]) + (part[6][t] + part[7][t]));
        (ws + WS_SG)[d0 + t] = v;
    }
}

// ---------------------------------------------------------------------------
// Partial Gram: block b covers d-chunk [64b, 64b+64); writes G_part[b][136].
// ---------------------------------------------------------------------------
__global__ __launch_bounds__(320) void moe_div_partial(
    const float* __restrict__ re,
    float* __restrict__ ws)
{
    __shared__ float reT[64][17];
    __shared__ float s_loc[64];

    const int t = threadIdx.x;
    const int b = blockIdx.x;
    const int d0 = b * 64;
    float* G_part = ws + WS_GP;

    if (t < 64) s_loc[t] = (ws + WS_SG)[d0 + t];
    if (t < 256) {
        int e = t >> 4, d4 = t & 15;
        float4 v = ((const float4*)(re + (size_t)e * DDIM + d0))[d4];
        reT[d4 * 4 + 0][e] = v.x;
        reT[d4 * 4 + 1][e] = v.y;
        reT[d4 * 4 + 2][e] = v.z;
        reT[d4 * 4 + 3][e] = v.w;
    }
    __syncthreads();

    const int p = t >> 1;
    const int half = t & 1;
    float a = 0.f;
    if (p < NPAIR) {
        int pe = 0, rem = p;
        while (rem >= NEXP - pe) { rem -= NEXP - pe; ++pe; }
        int pf = pe + rem;
        #pragma unroll
        for (int i = 0; i < 32; ++i) {
            int dd = half * 32 + i;
            a += s_loc[dd] * reT[dd][pe] * reT[dd][pf];
        }
    }
    a += __shfl_down(a, 1, 64);
    if (p < NPAIR && half == 0) G_part[b * NPAIR + p] = a;
}

// ---------------------------------------------------------------------------
// Finalize: sum 16 partial Grams, norms, clipped cosine mean * lambda.
// ---------------------------------------------------------------------------
__global__ __launch_bounds__(192) void moe_div_final(
    const float* __restrict__ ws,
    float* __restrict__ div_out)
{
    __shared__ float G[NPAIR];
    __shared__ float nr[NEXP];
    __shared__ float lsum;
    const float* G_part = ws + WS_GP;
    const int t = threadIdx.x;

    if (t == 0) lsum = 0.f;
    if (t < NPAIR) {
        float g = 0.f;
        #pragma unroll
        for (int b = 0; b < 16; ++b) g += G_part[b * NPAIR + t];
        G[t] = g;
    }
    __syncthreads();
    if (t < NEXP) {
        int idx = t * NEXP - (t * (t - 1)) / 2;
        nr[t] = fmaxf(sqrtf(G[idx]), 1e-8f);
    }
    __syncthreads();
    if (t < NPAIR) {
        int pe = 0, rem = t;
        while (rem >= NEXP - pe) { rem -= NEXP - pe; ++pe; }
        int pf = pe + rem;
        if (pe != pf) {
            float sim = G[t] / (nr[pe] * nr[pf]);
            sim = fminf(1.f, fmaxf(-1.f, sim));
            atomicAdd(&lsum, 2.f * sim);
        }
    }
    __syncthreads();
    if (t == 0) *div_out = lsum / (float)(NEXP * (NEXP - 1)) * 0.1f;
}

extern "C" void kernel_launch(void* const* d_in, const int* in_sizes, int n_in,
                              void* d_out, int out_size, void* d_ws, size_t ws_size,
                              hipStream_t stream) {
    const float* x  = (const float*)d_in[0];
    const float* gw = (const float*)d_in[1];
    const float* gb = (const float*)d_in[2];
    const float* sh = (const float*)d_in[3];
    const float* re = (const float*)d_in[4];
    float* out = (float*)d_out;
    float* ws = (float*)d_ws;

    const bool sred = ws_size >= (size_t)WS_NEED_F * sizeof(float);

    moe_prep<<<16, 256, 0, stream>>>(gw, ws);
    if (sred) {
        moe_fused<true><<<NBLK, 256, 0, stream>>>(x, gb, sh, re, out, ws);
        moe_sreduce<<<32, 256, 0, stream>>>(ws);
    } else {
        moe_fused<false><<<NBLK, 256, 0, stream>>>(x, gb, sh, re, out, ws);
    }
    moe_div_partial<<<16, 320, 0, stream>>>(re, ws);
    moe_div_final<<<1, 192, 0, stream>>>(ws, out + (size_t)NTOK * DDIM);
}